// Round 6
// baseline (212.688 us; speedup 1.0000x reference)
//
#include <hip/hip_runtime.h>
#include <hip/hip_cooperative_groups.h>

namespace cg = cooperative_groups;

// FUME epipolar translation, fp32 in/out. B from in_sizes[3]; C,H,W = 4,128,128.
//
// R17: SINGLE COOPERATIVE KERNEL (stage + grid.sync + main).
//  Budget after R12-R16: fill 40us (fixed harness poison) | stage+main ~8-9us
//  (R15 REP-probe: k-loop 2.6us; R16: stage shape-insensitive) | ~18-20us fixed
//  cost that tracks nothing inside the kernels -> theory: per-launch boundary
//  cost (queue drain + dispatch ramp) x2 launches. This round removes one
//  boundary: one cooperative launch, phase1 = cube build, grid.sync(),
//  phase2 = R11 main (best measured) x2 column-halves per block.
//  Grid 128*B=512 blocks x 512 thr, __launch_bounds__(512,4) -> VGPR<=128,
//  2 blocks/CU -> co-residency guaranteed for cooperative launch.
//  Per-entry and per-step math bit-identical to R11/R16 -> absmax 0.0625.
//
// Workspace (16B entries = {half2(tap0,tap1)}ch=0..3), row stride LDK=128:
//   horiz cube at entry ofs b*32768:        entry[u][s] = {img[ch][u][s], img[ch][u+1][s]}
//   vert  cube at entry ofs b*32768+16384:  entry[u][k] = {img[ch][k][u], img[ch][k][u+1]}
// (second tap clamped at the image edge; row u=127 is never read: i0<=126.)

#define CC 4
#define HH 128
#define WW 128
#define LDK 128              /* cube row stride, entries (16B each) */
#define CUBE (128 * LDK)     /* one direction cube, entries */

typedef _Float16 h2 __attribute__((ext_vector_type(2)));

__global__ void __launch_bounds__(512, 4) fume_fused(
        float4* __restrict__ ws,
        const float* __restrict__ img,
        const float* __restrict__ F,
        const float* __restrict__ dsf,
        float* __restrict__ out,
        int B) {
    int tx  = threadIdx.x;               // 0..63
    int seg = threadIdx.y;               // 0..7
    int bid = blockIdx.x;                // 0..128*B-1

    // ---------------- phase 1: build the two cubes ----------------
    {
        int gtid = bid * 512 + seg * 64 + tx;
        int nent = B << 15;              // B * 2 * CUBE
        if (gtid < nent) {
            int b   = gtid >> 15;
            int r   = gtid & 32767;
            int dir = r >> 14;           // 0 horiz, 1 vert
            int rr  = r & 16383;
            int u   = rr >> 7;           // cube row
            int t   = rr & 127;          // entry column
            const float* src = img + (size_t)b * CC * HH * WW;
            int u1 = min(u + 1, HH - 1);
            h2 p0, p1, p2, p3;
            if (dir == 0) {
                // horiz: entry[u][t] = {img[ch][u][t], img[ch][u1][t]}
                p0 = (h2){ (_Float16)src[(0 * HH + u) * WW + t], (_Float16)src[(0 * HH + u1) * WW + t] };
                p1 = (h2){ (_Float16)src[(1 * HH + u) * WW + t], (_Float16)src[(1 * HH + u1) * WW + t] };
                p2 = (h2){ (_Float16)src[(2 * HH + u) * WW + t], (_Float16)src[(2 * HH + u1) * WW + t] };
                p3 = (h2){ (_Float16)src[(3 * HH + u) * WW + t], (_Float16)src[(3 * HH + u1) * WW + t] };
            } else {
                // vert: entry[u][t] = {img[ch][t][u], img[ch][t][u1]}
                p0 = (h2){ (_Float16)src[(0 * HH + t) * WW + u], (_Float16)src[(0 * HH + t) * WW + u1] };
                p1 = (h2){ (_Float16)src[(1 * HH + t) * WW + u], (_Float16)src[(1 * HH + t) * WW + u1] };
                p2 = (h2){ (_Float16)src[(2 * HH + t) * WW + u], (_Float16)src[(2 * HH + t) * WW + u1] };
                p3 = (h2){ (_Float16)src[(3 * HH + t) * WW + u], (_Float16)src[(3 * HH + t) * WW + u1] };
            }
            ws[((size_t)b * 2 + dir) * CUBE + u * LDK + t] =
                make_float4(__builtin_bit_cast(float, p0),
                            __builtin_bit_cast(float, p1),
                            __builtin_bit_cast(float, p2),
                            __builtin_bit_cast(float, p3));
        }
    }
    __threadfence();                     // device-scope release (cross-XCD)
    cg::this_grid().sync();

    // ---------------- phase 2: R11 main, two column-halves ----------------
    int y = bid & 127;
    int b = bid >> 7;

    float d = dsf[b];
    float F00 = F[0], F01 = F[1], F02 = F[2];
    float F10 = F[3], F11 = F[4], F12 = F[5];
    float F20 = F[6], F21 = F[7], F22 = F[8];

    const float4* cb = ws + (size_t)b * (2 * CUBE);
    __shared__ float part[8][4][64];

    for (int xh = 0; xh < 2; ++xh) {
        int x = xh * 64 + tx;

        // Exact reference op order (no fma contraction).
        float px = __fmul_rn((float)x, d);
        float py = __fmul_rn((float)y, d);
        float av = __fadd_rn(__fadd_rn(__fmul_rn(F00, px), __fmul_rn(F01, py)), F02);
        float bv = __fadd_rn(__fadd_rn(__fmul_rn(F10, px), __fmul_rn(F11, py)), F12);
        float cv = __fadd_rn(__fadd_rn(__fmul_rn(F20, px), __fmul_rn(F21, py)), F22);

        bool horiz  = fabsf(bv) >= fabsf(av);
        float ncoef = horiz ? av : bv;
        float den   = __fmul_rn(horiz ? bv : av, d);
        float nrec  = -__fdiv_rn(1.0f, den);   // den 0/Inf/NaN -> u NaN -> masked

        const float4* P = cb + (horiz ? 0 : CUBE);

        // Conservative valid-k interval, PER LANE (exact mask still applied).
        float A  = __fmul_rn(__fmul_rn(ncoef, d), nrec);
        float Bc = __fmul_rn(cv, nrec);
        int lkmin, lkmax;
        if (fabsf(A) > 1e-20f) {
            float inv = 1.0f / A;
            float k1 = (0.0f   - Bc) * inv;
            float k2 = (127.0f - Bc) * inv;
            float lo = fmaxf(fminf(k1, k2) - 2.0f, 0.0f);
            float hi = fminf(fmaxf(k1, k2) + 2.0f, 127.0f);
            if (lo > hi || !(lo == lo)) { lkmin = 1; lkmax = 0; }
            else { lkmin = (int)lo; lkmax = (int)hi; }
        } else {
            bool full = (Bc >= 0.0f) && (Bc <= 127.0f);
            lkmin = full ? 0 : 1;
            lkmax = full ? 127 : 0;
        }

        float a0 = 0.f, a1 = 0.f, a2 = 0.f, a3 = 0.f;
        int len = lkmax - lkmin + 1;          // may be <=0 (empty)
        int cnt = (len + 7) >> 3;             // steps per seg for THIS lane
        int ks  = lkmin + seg * cnt;
        int ke  = min(ks + cnt - 1, lkmax);   // empty if len<=0
        #pragma unroll 8
        for (int k = ks; k <= ke; ++k) {
            float m  = __fmul_rn((float)k, d);
            float q  = __fadd_rn(__fmul_rn(ncoef, m), cv);
            float u  = __fmul_rn(q, nrec);
            bool ok  = (u >= 0.f) && (u <= 127.f);
            int i0   = (int)floorf(u);        // NaN->0, sat; clamped next
            i0 = max(0, min(i0, 126));
            float w  = __fsub_rn(u, (float)i0);   // ==1 at u==127 -> row[127]
            h2 wp = __builtin_bit_cast(h2,
                        __builtin_amdgcn_cvt_pkrtz(__fsub_rn(1.f, w), w));
            wp = ok ? wp : (h2){(_Float16)0.f, (_Float16)0.f};
            float4 e = P[i0 * LDK + k];       // transposed [u][k] cube
            a0 = __builtin_amdgcn_fdot2(wp, __builtin_bit_cast(h2, e.x), a0, false);
            a1 = __builtin_amdgcn_fdot2(wp, __builtin_bit_cast(h2, e.y), a1, false);
            a2 = __builtin_amdgcn_fdot2(wp, __builtin_bit_cast(h2, e.z), a2, false);
            a3 = __builtin_amdgcn_fdot2(wp, __builtin_bit_cast(h2, e.w), a3, false);
        }

        part[seg][0][tx] = a0;
        part[seg][1][tx] = a1;
        part[seg][2][tx] = a2;
        part[seg][3][tx] = a3;
        __syncthreads();

        if (seg < 4) {                            // waves 0..3: one channel each
            int ch = seg;
            float s = part[0][ch][tx];
            #pragma unroll
            for (int t = 1; t < 8; ++t) s = __fadd_rn(s, part[t][ch][tx]);
            out[(((size_t)b * CC + ch) * HH + y) * WW + x] = s;
        }
        __syncthreads();                          // part[] reused by next xh
    }
}

extern "C" void kernel_launch(void* const* d_in, const int* in_sizes, int n_in,
                              void* d_out, int out_size, void* d_ws, size_t ws_size,
                              hipStream_t stream) {
    const float* view1 = (const float*)d_in[0];
    const float* F21   = (const float*)d_in[1];
    const float* dsf   = (const float*)d_in[3];
    float* outp        = (float*)d_out;
    float4* ws         = (float4*)d_ws;

    int B = in_sizes[3];

    void* args[] = { (void*)&ws, (void*)&view1, (void*)&F21, (void*)&dsf,
                     (void*)&outp, (void*)&B };
    hipLaunchCooperativeKernel((void*)fume_fused,
                               dim3(128 * B, 1, 1), dim3(64, 8, 1),
                               args, 0, stream);
}

// Round 7
// 81.447 us; speedup vs baseline: 2.6114x; 2.6114x over previous
//
#include <hip/hip_runtime.h>

// FUME epipolar translation, fp32 in/out. B from in_sizes[3]; C,H,W = 4,128,128.
//
// R18: SINGLE REGULAR LAUNCH, NO WORKSPACE. Direct fp32-image sampling.
//  Budget (R15 REP-probe + R17 coop-probe): fill 40us (immutable harness poison
//  of the full 256MiB ws) | kernels ~9us | ~20us envelope, part per-boundary.
//  R17 proved grid.sync costs ~135us -> cooperative fusion dead. This round
//  removes the stage kernel AND one launch boundary: main samples img directly.
//  Per k-step: 8 scalar dword loads (4ch x 2 taps, planar) instead of one
//  dwordx4 cube entry; branchless offsets (o0 = horiz? i0*W+k : k*W+i0,
//  o1 = o0 + (horiz? W : 1)) -> no exec divergence. Taps go through the same
//  (_Float16) cast into the same fdot2, same R11 summation order -> output
//  bit-identical to R11/R16 (absmax 0.0625). Image is 1MB -> L2-resident;
//  R14 null says line-count doesn't matter, only issue count (k-loop ~2.6us
//  -> ~8us predicted).
//
// Main structure = R11 (best measured 67.2us): 8 seg-waves x 64 pixels,
// per-lane conservative k-intervals, LDS part[] reduction, waves 0..3 write
// one channel each.

#define CC 4
#define HH 128
#define WW 128
#define HW (HH * WW)

typedef _Float16 h2 __attribute__((ext_vector_type(2)));

__global__ void __launch_bounds__(512) fume_kernel(
        const float* __restrict__ img,
        const float* __restrict__ F,
        const float* __restrict__ dsf,
        float* __restrict__ out) {
    int tx  = threadIdx.x;               // 0..63 : x within group (one wave)
    int seg = threadIdx.y;               // 0..7  : k-segment (wave id)
    int x = blockIdx.x * 64 + tx;
    int y = blockIdx.y;
    int b = blockIdx.z;

    float d = dsf[b];
    float F00 = F[0], F01 = F[1], F02 = F[2];
    float F10 = F[3], F11 = F[4], F12 = F[5];
    float F20 = F[6], F21 = F[7], F22 = F[8];

    // Exact reference op order (no fma contraction).
    float px = __fmul_rn((float)x, d);
    float py = __fmul_rn((float)y, d);
    float av = __fadd_rn(__fadd_rn(__fmul_rn(F00, px), __fmul_rn(F01, py)), F02);
    float bv = __fadd_rn(__fadd_rn(__fmul_rn(F10, px), __fmul_rn(F11, py)), F12);
    float cv = __fadd_rn(__fadd_rn(__fmul_rn(F20, px), __fmul_rn(F21, py)), F22);

    bool horiz  = fabsf(bv) >= fabsf(av);
    float ncoef = horiz ? av : bv;
    float den   = __fmul_rn(horiz ? bv : av, d);
    float nrec  = -__fdiv_rn(1.0f, den);   // den 0/Inf/NaN -> u NaN -> masked

    const float* sb = img + (size_t)b * CC * HW;

    // Conservative valid-k interval, PER LANE (exact mask still applied).
    float A  = __fmul_rn(__fmul_rn(ncoef, d), nrec);
    float Bc = __fmul_rn(cv, nrec);
    int lkmin, lkmax;
    if (fabsf(A) > 1e-20f) {
        float inv = 1.0f / A;
        float k1 = (0.0f   - Bc) * inv;
        float k2 = (127.0f - Bc) * inv;
        float lo = fmaxf(fminf(k1, k2) - 2.0f, 0.0f);
        float hi = fminf(fmaxf(k1, k2) + 2.0f, 127.0f);
        if (lo > hi || !(lo == lo)) { lkmin = 1; lkmax = 0; }
        else { lkmin = (int)lo; lkmax = (int)hi; }
    } else {
        bool full = (Bc >= 0.0f) && (Bc <= 127.0f);
        lkmin = full ? 0 : 1;
        lkmax = full ? 127 : 0;
    }

    // Branchless tap-offset parameters (o1 = o0 + ostep).
    int ostep = horiz ? WW : 1;

    float a0 = 0.f, a1 = 0.f, a2 = 0.f, a3 = 0.f;
    int len = lkmax - lkmin + 1;          // may be <=0 (empty)
    int cnt = (len + 7) >> 3;             // steps per seg for THIS lane
    int ks  = lkmin + seg * cnt;
    int ke  = min(ks + cnt - 1, lkmax);   // empty if len<=0
    #pragma unroll 4
    for (int k = ks; k <= ke; ++k) {
        float m  = __fmul_rn((float)k, d);
        float q  = __fadd_rn(__fmul_rn(ncoef, m), cv);
        float u  = __fmul_rn(q, nrec);
        bool ok  = (u >= 0.f) && (u <= 127.f);
        int i0   = (int)floorf(u);        // NaN->0, sat; clamped next
        i0 = max(0, min(i0, 126));
        float w  = __fsub_rn(u, (float)i0);   // ==1 at u==127 -> row/col[127]
        h2 wp = __builtin_bit_cast(h2,
                    __builtin_amdgcn_cvt_pkrtz(__fsub_rn(1.f, w), w));
        wp = ok ? wp : (h2){(_Float16)0.f, (_Float16)0.f};
        // horiz: taps img[ch][i0][k], img[ch][i0+1][k]
        // vert : taps img[ch][k][i0], img[ch][k][i0+1]
        int o0 = horiz ? (i0 * WW + k) : (k * WW + i0);
        int o1 = o0 + ostep;
        {
            h2 e0 = { (_Float16)sb[0 * HW + o0], (_Float16)sb[0 * HW + o1] };
            h2 e1 = { (_Float16)sb[1 * HW + o0], (_Float16)sb[1 * HW + o1] };
            h2 e2 = { (_Float16)sb[2 * HW + o0], (_Float16)sb[2 * HW + o1] };
            h2 e3 = { (_Float16)sb[3 * HW + o0], (_Float16)sb[3 * HW + o1] };
            a0 = __builtin_amdgcn_fdot2(wp, e0, a0, false);
            a1 = __builtin_amdgcn_fdot2(wp, e1, a1, false);
            a2 = __builtin_amdgcn_fdot2(wp, e2, a2, false);
            a3 = __builtin_amdgcn_fdot2(wp, e3, a3, false);
        }
    }

    __shared__ float part[8][4][64];
    part[seg][0][tx] = a0;
    part[seg][1][tx] = a1;
    part[seg][2][tx] = a2;
    part[seg][3][tx] = a3;
    __syncthreads();

    if (seg < 4) {                                // waves 0..3: one channel each
        int ch = seg;
        float s = part[0][ch][tx];
        #pragma unroll
        for (int t = 1; t < 8; ++t) s = __fadd_rn(s, part[t][ch][tx]);
        out[(((size_t)b * CC + ch) * HH + y) * WW + x] = s;
    }
}

extern "C" void kernel_launch(void* const* d_in, const int* in_sizes, int n_in,
                              void* d_out, int out_size, void* d_ws, size_t ws_size,
                              hipStream_t stream) {
    const float* view1 = (const float*)d_in[0];
    const float* F21   = (const float*)d_in[1];
    const float* dsf   = (const float*)d_in[3];

    const int B = in_sizes[3];

    dim3 ftb(64, 8, 1);
    dim3 ftg(WW / 64, HH, B);
    fume_kernel<<<ftg, ftb, 0, stream>>>(view1, F21, dsf, (float*)d_out);
}

// Round 8
// 67.778 us; speedup vs baseline: 3.1380x; 1.2017x over previous
//
#include <hip/hip_runtime.h>

// FUME epipolar translation, fp32 in/out. B from in_sizes[3]; C,H,W = 4,128,128.
//
// R19 = R11 REVERT (best measured: 67.2us). Session budget, fully accounted:
//   ~40us  harness ws-poison fill (unconditional — runs even with ws unused, R18;
//          at 84% HBM peak = its own roofline)
//   ~18-20us fixed envelope (R17 single-launch residual == R16 two-launch residual)
//   ~2us   launch boundary (R18 isolation)
//   ~7-8us stage+main (R15 REP-probe: k-loop 2.6us; R16: stage shape-insensitive)
// Theories tested and killed: L2-channel aliasing (R12 pad, neutral);
// wave-per-pixel (R13, -12); octet line-traffic halving (R14, neutral);
// stage-v3 (R16, neutral); cooperative fusion (R17, grid.sync ~135us);
// direct sampling / no-ws (R18, -14; fill is unconditional).
// Controllable region ~7-8us, noise +-2.5us -> R11 structure is the optimum.
//
// Structure: stage builds two fp16-pair cubes in ws; main = 8 seg-waves x 64
// pixels, per-lane conservative k-intervals, dwordx4 cube gather + fdot2,
// LDS part[] reduction, waves 0..3 write one channel each.
//
// Workspace (16B entries = {half2(v[ch][u],v[ch][u+1])}ch=0..3):
//   horiz cube at entry ofs b*32768:        row r=x, col u=y : taps img[ch][u][x], img[ch][u+1][x]
//   vert  cube at entry ofs b*32768+16384:  row r=y, col u=x : taps img[ch][r][u], img[ch][r][u+1]
// (tap u+1 clamped at the image edge; entry col 127 is never read: i0<=126.)

#define CC 4
#define HH 128
#define WW 128

typedef _Float16 h2 __attribute__((ext_vector_type(2)));

__global__ void __launch_bounds__(256) fume_stage(
        const float* __restrict__ img, float4* __restrict__ ws) {
    __shared__ float tile[4][17][17];
    int x0 = blockIdx.x * 16, y0 = blockIdx.y * 16, b = blockIdx.z;
    int tx = threadIdx.x, ty = threadIdx.y;   // 16x16
    int id = ty * 16 + tx;
    const float* src = img + (size_t)b * CC * HH * WW;

    #pragma unroll
    for (int ch = 0; ch < 4; ++ch) {
        #pragma unroll
        for (int e = 0; e < 2; ++e) {
            int idx = id + e * 256;
            if (idx < 289) {
                int i = idx / 17, j = idx % 17;
                int r = min(y0 + i, HH - 1);
                int c = min(x0 + j, WW - 1);
                tile[ch][i][j] = src[(ch * HH + r) * WW + c];
            }
        }
    }
    __syncthreads();

    float4* base_h = ws + (size_t)b * 32768;
    float4* base_v = base_h + 16384;

    // vert entry: k = y0+ty, u = x0+tx : taps tile[ch][ty][tx], tile[ch][ty][tx+1]
    {
        h2 p0 = { (_Float16)tile[0][ty][tx], (_Float16)tile[0][ty][tx + 1] };
        h2 p1 = { (_Float16)tile[1][ty][tx], (_Float16)tile[1][ty][tx + 1] };
        h2 p2 = { (_Float16)tile[2][ty][tx], (_Float16)tile[2][ty][tx + 1] };
        h2 p3 = { (_Float16)tile[3][ty][tx], (_Float16)tile[3][ty][tx + 1] };
        float4 e = make_float4(__builtin_bit_cast(float, p0),
                               __builtin_bit_cast(float, p1),
                               __builtin_bit_cast(float, p2),
                               __builtin_bit_cast(float, p3));
        base_v[(y0 + ty) * WW + (x0 + tx)] = e;
    }
    // horiz entry: r = x0+ty, u = y0+tx : taps tile[ch][tx][ty], tile[ch][tx+1][ty]
    {
        h2 p0 = { (_Float16)tile[0][tx][ty], (_Float16)tile[0][tx + 1][ty] };
        h2 p1 = { (_Float16)tile[1][tx][ty], (_Float16)tile[1][tx + 1][ty] };
        h2 p2 = { (_Float16)tile[2][tx][ty], (_Float16)tile[2][tx + 1][ty] };
        h2 p3 = { (_Float16)tile[3][tx][ty], (_Float16)tile[3][tx + 1][ty] };
        float4 e = make_float4(__builtin_bit_cast(float, p0),
                               __builtin_bit_cast(float, p1),
                               __builtin_bit_cast(float, p2),
                               __builtin_bit_cast(float, p3));
        base_h[(x0 + ty) * HH + (y0 + tx)] = e;
    }
}

__global__ void __launch_bounds__(512) fume_kernel(
        const float4* __restrict__ cubes,
        const float* __restrict__ F,
        const float* __restrict__ dsf,
        float* __restrict__ out) {
    int tx  = threadIdx.x;               // 0..63 : x within group (one wave)
    int seg = threadIdx.y;               // 0..7  : k-segment (wave id)
    int x = blockIdx.x * 64 + tx;
    int y = blockIdx.y;
    int b = blockIdx.z;

    float d = dsf[b];
    float F00 = F[0], F01 = F[1], F02 = F[2];
    float F10 = F[3], F11 = F[4], F12 = F[5];
    float F20 = F[6], F21 = F[7], F22 = F[8];

    // Exact reference op order (no fma contraction).
    float px = __fmul_rn((float)x, d);
    float py = __fmul_rn((float)y, d);
    float av = __fadd_rn(__fadd_rn(__fmul_rn(F00, px), __fmul_rn(F01, py)), F02);
    float bv = __fadd_rn(__fadd_rn(__fmul_rn(F10, px), __fmul_rn(F11, py)), F12);
    float cv = __fadd_rn(__fadd_rn(__fmul_rn(F20, px), __fmul_rn(F21, py)), F22);

    bool horiz  = fabsf(bv) >= fabsf(av);
    float ncoef = horiz ? av : bv;
    float den   = __fmul_rn(horiz ? bv : av, d);
    float nrec  = -__fdiv_rn(1.0f, den);   // den 0/Inf/NaN -> u NaN -> masked

    const float4* P = cubes + (size_t)b * 32768 + (horiz ? 0 : 16384);

    // Conservative valid-k interval, PER LANE (exact mask still applied).
    float A  = __fmul_rn(__fmul_rn(ncoef, d), nrec);
    float Bc = __fmul_rn(cv, nrec);
    int lkmin, lkmax;
    if (fabsf(A) > 1e-20f) {
        float inv = 1.0f / A;
        float k1 = (0.0f   - Bc) * inv;
        float k2 = (127.0f - Bc) * inv;
        float lo = fmaxf(fminf(k1, k2) - 2.0f, 0.0f);
        float hi = fminf(fmaxf(k1, k2) + 2.0f, 127.0f);
        if (lo > hi || !(lo == lo)) { lkmin = 1; lkmax = 0; }
        else { lkmin = (int)lo; lkmax = (int)hi; }
    } else {
        bool full = (Bc >= 0.0f) && (Bc <= 127.0f);
        lkmin = full ? 0 : 1;
        lkmax = full ? 127 : 0;
    }

    float a0 = 0.f, a1 = 0.f, a2 = 0.f, a3 = 0.f;
    int len = lkmax - lkmin + 1;          // may be <=0 (empty)
    int cnt = (len + 7) >> 3;             // steps per seg for THIS lane
    int ks  = lkmin + seg * cnt;
    int ke  = min(ks + cnt - 1, lkmax);   // empty if len<=0
    #pragma unroll 8
    for (int k = ks; k <= ke; ++k) {
        float m  = __fmul_rn((float)k, d);
        float q  = __fadd_rn(__fmul_rn(ncoef, m), cv);
        float u  = __fmul_rn(q, nrec);
        bool ok  = (u >= 0.f) && (u <= 127.f);
        int i0   = (int)floorf(u);        // NaN->0, sat; clamped next
        i0 = max(0, min(i0, 126));
        float w  = __fsub_rn(u, (float)i0);   // ==1 at u==127 -> row[127]
        h2 wp = __builtin_bit_cast(h2,
                    __builtin_amdgcn_cvt_pkrtz(__fsub_rn(1.f, w), w));
        wp = ok ? wp : (h2){(_Float16)0.f, (_Float16)0.f};
        float4 e = P[k * 128 + i0];
        a0 = __builtin_amdgcn_fdot2(wp, __builtin_bit_cast(h2, e.x), a0, false);
        a1 = __builtin_amdgcn_fdot2(wp, __builtin_bit_cast(h2, e.y), a1, false);
        a2 = __builtin_amdgcn_fdot2(wp, __builtin_bit_cast(h2, e.z), a2, false);
        a3 = __builtin_amdgcn_fdot2(wp, __builtin_bit_cast(h2, e.w), a3, false);
    }

    __shared__ float part[8][4][64];
    part[seg][0][tx] = a0;
    part[seg][1][tx] = a1;
    part[seg][2][tx] = a2;
    part[seg][3][tx] = a3;
    __syncthreads();

    if (seg < 4) {                                // waves 0..3: one channel each
        int ch = seg;
        float s = part[0][ch][tx];
        #pragma unroll
        for (int t = 1; t < 8; ++t) s = __fadd_rn(s, part[t][ch][tx]);
        out[(((size_t)b * CC + ch) * HH + y) * WW + x] = s;
    }
}

extern "C" void kernel_launch(void* const* d_in, const int* in_sizes, int n_in,
                              void* d_out, int out_size, void* d_ws, size_t ws_size,
                              hipStream_t stream) {
    const float* view1 = (const float*)d_in[0];
    const float* F21   = (const float*)d_in[1];
    const float* dsf   = (const float*)d_in[3];

    const int B = in_sizes[3];

    dim3 stb(16, 16, 1);
    dim3 stg(WW / 16, HH / 16, B);
    fume_stage<<<stg, stb, 0, stream>>>(view1, (float4*)d_ws);

    dim3 ftb(64, 8, 1);
    dim3 ftg(WW / 64, HH, B);
    fume_kernel<<<ftg, ftb, 0, stream>>>((const float4*)d_ws, F21, dsf,
                                         (float*)d_out);
}